// Round 7
// baseline (1661.484 us; speedup 1.0000x reference)
//
#include <hip/hip_runtime.h>
#include <cstddef>

constexpr int B_ = 64, S_ = 512, E_ = 512, H_ = 8, D_ = 64, L_ = 4, O_ = 1000;
constexpr int BS_ = B_ * S_;        // 32768
constexpr int HD_ = H_ * D_;        // 512
constexpr int QS_ = 1536;           // fused QKV row stride
constexpr int LOUT_ = 102;
constexpr float SCALE_ = 0.04419417382415922f;   // 1/sqrt(512)
constexpr float SCALE2_ = SCALE_ * 1.4426950408889634f;  // fold log2(e): exp2 softmax

typedef __bf16 bf16x8 __attribute__((ext_vector_type(8)));
typedef __bf16 bf16x4 __attribute__((ext_vector_type(4)));
typedef __bf16 bf16x2 __attribute__((ext_vector_type(2)));
typedef float floatx4 __attribute__((ext_vector_type(4)));

__device__ inline void load16_lds(const __bf16* g, __bf16* l) {
  __builtin_amdgcn_global_load_lds(
      (const __attribute__((address_space(1))) void*)g,
      (__attribute__((address_space(3))) void*)l, 16, 0, 0);
}

// ---------------- weight transpose + bf16 convert ----------------
// in: fp32 [R][C] (z-slice at z*IZ). out: bf16 [C][R] at (z>>3)*OZL + (z&7)*OZH.
__global__ __launch_bounds__(256) void transpose_bf16(
    const float* __restrict__ in, __bf16* __restrict__ out,
    int R, int C, int IZ, int OZL, int OZH) {
  __shared__ float t[32][33];
  int z = blockIdx.z;
  const float* inz = in + (size_t)z * IZ;
  __bf16* outz = out + (size_t)(z >> 3) * OZL + (size_t)(z & 7) * OZH;
  int c0 = blockIdx.x * 32, r0 = blockIdx.y * 32;
  int x = threadIdx.x, y = threadIdx.y;  // (32,8)
#pragma unroll
  for (int j = 0; j < 32; j += 8) t[y + j][x] = inz[(size_t)(r0 + y + j) * C + c0 + x];
  __syncthreads();
#pragma unroll
  for (int j = 0; j < 32; j += 8)
    outz[(size_t)(c0 + y + j) * R + r0 + x] = (__bf16)t[x][y + j];
}

// ---------------- concat qkv bias: [L][1536] = bq|bk|bv ----------------
__global__ __launch_bounds__(256) void bias_concat(
    const float* __restrict__ bq, const float* __restrict__ bk,
    const float* __restrict__ bv, float* __restrict__ qkvb) {
  int idx = blockIdx.x * 256 + threadIdx.x;  // < 6144
  int l = idx / QS_, j = idx % QS_;
  float v;
  if (j < 512) v = bq[l * 512 + j];
  else if (j < 1024) v = bk[l * 512 + j - 512];
  else v = bv[l * 512 + j - 1024];
  qkvb[idx] = v;
}

// ---------------- embedding + mask -> X fp32 + Ab bf16 ----------------
__global__ __launch_bounds__(256) void embed_kernel(
    const int* __restrict__ tokens, const float* __restrict__ emb,
    float* __restrict__ X, __bf16* __restrict__ Ab) {
  int idx = blockIdx.x * 256 + threadIdx.x;  // float4 index
  int bs = idx >> 7;
  int e = (idx & 127) << 2;
  int tok = tokens[bs];
  float4 v;
  if (tok == 0) v = make_float4(0.f, 0.f, 0.f, 0.f);
  else v = *(const float4*)(emb + (size_t)tok * E_ + e);
  size_t off = (size_t)bs * E_ + e;
  *(float4*)(X + off) = v;
  bf16x4 b;
  b[0] = (__bf16)v.x; b[1] = (__bf16)v.y; b[2] = (__bf16)v.z; b[3] = (__bf16)v.w;
  *(bf16x4*)(Ab + off) = b;
}

// ---------------- bf16 MFMA GEMM (m97-style, BK=64, xor-swizzled LDS) ------
// C[M,N] = act(A[M,K] @ B + bias (+ Rsd)).  Bt is [N][K] (B transposed).
// 1D grid of (Mt*Nt) blocks, XCD-aware swizzle: id&7 picks a private m-range
// (Mt/8 tiles); within it, n iterates fastest over chunks of 2 m-tiles, so
// the concurrent per-XCD L2 footprint is 2 A-tiles + the whole B slab (<4MB).
// MFMA operands swapped (D holds C^T fragments): lane owns row m = a_,
// 4 consecutive cols n = jc*16 + q4*4 + r  -> vectorized epilogue.
// bf16 C staged through LDS (pad 136) -> 256B-contiguous coalesced stores.
template <int RELU, int RES, int OUTF, int OUTB, int SCQ, int KITER>
__global__ __launch_bounds__(256) void gemm_bf16(
    const __bf16* __restrict__ A, const __bf16* __restrict__ Bt,
    const float* __restrict__ bias, const float* __restrict__ Rsd,
    float* __restrict__ Cf, __bf16* __restrict__ Cb, int N, int lda, int Nt) {
  __shared__ __align__(16) __bf16 smem[128 * 136];  // As | Bs overlay, then Cs
  __bf16* As = smem;
  __bf16* Bs = smem + 8192;
  int tid = threadIdx.x;
  int lane = tid & 63, w = tid >> 6;
  // XCD-aware swizzle
  int Mt8 = (int)(gridDim.x / Nt) >> 3;       // m-tiles per XCD range
  int xcd = blockIdx.x & 7;
  int j = blockIdx.x >> 3;
  int rr = j % (2 * Nt), chunk = j / (2 * Nt);
  int mt = xcd * Mt8 + chunk * 2 + (rr & 1);
  int nt = rr >> 1;
  int m0 = mt * 128, n0 = nt * 128;
  int q4 = lane >> 4, a_ = lane & 15;
  floatx4 acc[4][4];
#pragma unroll
  for (int i = 0; i < 4; ++i)
#pragma unroll
    for (int jj = 0; jj < 4; ++jj) acc[i][jj] = (floatx4)(0.0f);

  for (int kk = 0; kk < KITER; ++kk) {
    int k0 = kk * 64;
#pragma unroll
    for (int jj = 0; jj < 4; ++jj) {
      int ci = (jj * 4 + w) * 64 + lane;
      int row = ci >> 3, c = ci & 7, q = c ^ (row & 7);
      load16_lds(A + (size_t)(m0 + row) * lda + k0 + q * 8, As + (size_t)(jj * 4 + w) * 512);
    }
#pragma unroll
    for (int jj = 0; jj < 4; ++jj) {
      int ci = (jj * 4 + w) * 64 + lane;
      int row = ci >> 3, c = ci & 7, q = c ^ (row & 7);
      load16_lds(Bt + (size_t)(n0 + row) * (KITER * 64) + k0 + q * 8,
                 Bs + (size_t)(jj * 4 + w) * 512);
    }
    __syncthreads();
#pragma unroll
    for (int ks = 0; ks < 2; ++ks) {
      bf16x8 af[4], bfr[4];
#pragma unroll
      for (int i = 0; i < 4; ++i) {
        int row = (w & 1) * 64 + i * 16 + a_;
        int q = ks * 4 + q4;
        af[i] = *(const bf16x8*)&As[(row * 8 + (q ^ (row & 7))) * 8];
      }
#pragma unroll
      for (int jc = 0; jc < 4; ++jc) {
        int row = (w >> 1) * 64 + jc * 16 + a_;
        int q = ks * 4 + q4;
        bfr[jc] = *(const bf16x8*)&Bs[(row * 8 + (q ^ (row & 7))) * 8];
      }
#pragma unroll
      for (int i = 0; i < 4; ++i)
#pragma unroll
        for (int jc = 0; jc < 4; ++jc)
          acc[i][jc] = __builtin_amdgcn_mfma_f32_16x16x32_bf16(bfr[jc], af[i],
                                                               acc[i][jc], 0, 0, 0);
    }
    __syncthreads();
  }
  // ---- epilogue: vectorized, bf16 staged via LDS ----
#pragma unroll
  for (int i = 0; i < 4; ++i) {
    int ml = (w & 1) * 64 + i * 16 + a_;
    int m = m0 + ml;
#pragma unroll
    for (int jc = 0; jc < 4; ++jc) {
      int nl = (w >> 1) * 64 + jc * 16 + q4 * 4;
      int n = n0 + nl;
      float4 bi = *(const float4*)(bias + n);
      floatx4 v = acc[i][jc];
      v[0] += bi.x; v[1] += bi.y; v[2] += bi.z; v[3] += bi.w;
      if (SCQ) { if (n < 512) v *= SCALE2_; }
      if (RES) {
        float4 rv = *(const float4*)(Rsd + (size_t)m * N + n);
        v[0] += rv.x; v[1] += rv.y; v[2] += rv.z; v[3] += rv.w;
      }
      if (RELU) {
#pragma unroll
        for (int r = 0; r < 4; ++r) v[r] = fmaxf(v[r], 0.f);
      }
      if (OUTF) {
        float4 o = make_float4(v[0], v[1], v[2], v[3]);
        *(float4*)(Cf + (size_t)m * N + n) = o;
      }
      if (OUTB) {
        bf16x4 ob;
#pragma unroll
        for (int r = 0; r < 4; ++r) ob[r] = (__bf16)v[r];
        *(bf16x4*)&smem[ml * 136 + nl] = ob;
      }
    }
  }
  if (OUTB) {
    __syncthreads();
#pragma unroll
    for (int it = 0; it < 8; ++it) {
      int cid = it * 256 + tid;
      int row = cid >> 4, c8 = cid & 15;
      bf16x8 val = *(const bf16x8*)&smem[row * 136 + c8 * 8];
      *(bf16x8*)(Cb + (size_t)(m0 + row) * N + n0 + c8 * 8) = val;
    }
  }
}

// ---------------- MFMA flash attention v3 (128-row slab, exp2 softmax) -----
// block = (b, h, 128-row Q slab); 4 waves; wave w owns s-chunks (cc*4+w)*16,
// cc in {0,1}. LDS = 40KB -> 4 blocks/CU. Q pre-scaled by log2(e)/sqrt(E) in
// the QKV epilogue, so softmax uses exp2 (single v_exp_f32). Heads written
// in-place over the Q slice.
__global__ __launch_bounds__(256, 4) void attn_bf16(__bf16* __restrict__ QKV) {
  __shared__ __align__(16) __bf16 Qs[128 * 64];  // swizzled chunks (16 KB)
  __shared__ __align__(16) __bf16 Ks[64 * 64];   // swizzled (8 KB)
  __shared__ __align__(16) __bf16 Vt[64 * 64];   // V^T [d][t], swizzled (8 KB)
  __shared__ __align__(16) __bf16 Ps[64 * 64];   // P bands per wave (8 KB)
  int tid = threadIdx.x, lane = tid & 63, w = tid >> 6;
  int q4 = lane >> 4, a_ = lane & 15;
  int s0 = blockIdx.x * 128, h = blockIdx.y, b = blockIdx.z;
  size_t rowbase = (size_t)b * S_ * QS_ + h * 64;
  __bf16* Qg = QKV + rowbase;
  const __bf16* Kg = QKV + rowbase + 512;
  const __bf16* Vg = QKV + rowbase + 1024;
  // stage Q slab (128 rows), swizzled
#pragma unroll
  for (int j = 0; j < 4; ++j) {
    int ci = j * 256 + tid;
    int row = ci >> 3, c = ci & 7, q = c ^ (row & 7);
    load16_lds(Qg + (size_t)(s0 + row) * QS_ + q * 8, Qs + (j * 256 + w * 64) * 8);
  }
  float mrow[2], lrow[2];
  floatx4 accO[2][4];
#pragma unroll
  for (int cc = 0; cc < 2; ++cc) {
    mrow[cc] = -3.0e38f; lrow[cc] = 0.f;
#pragma unroll
    for (int jc = 0; jc < 4; ++jc) accO[cc][jc] = (floatx4)(0.0f);
  }

  for (int t0 = 0; t0 < S_; t0 += 64) {
    // stage K tile, swizzled
#pragma unroll
    for (int j = 0; j < 2; ++j) {
      int ci = j * 256 + tid;
      int row = ci >> 3, c = ci & 7, q = c ^ (row & 7);
      load16_lds(Kg + (size_t)(t0 + row) * QS_ + q * 8, Ks + (j * 256 + w * 64) * 8);
    }
    // stage V transposed -> Vt[d][t], swizzled chunks
    {
      int tp = tid & 31, dg = tid >> 5;
      bf16x8 v0 = *(const bf16x8*)(Vg + (size_t)(t0 + 2 * tp) * QS_ + dg * 8);
      bf16x8 v1 = *(const bf16x8*)(Vg + (size_t)(t0 + 2 * tp + 1) * QS_ + dg * 8);
#pragma unroll
      for (int x = 0; x < 8; ++x) {
        int d = dg * 8 + x;
        bf16x2 p; p[0] = v0[x]; p[1] = v1[x];
        *(bf16x2*)&Vt[(d * 8 + ((tp >> 2) ^ (d & 7))) * 8 + (tp & 3) * 2] = p;
      }
    }
    __syncthreads();
    // K and V^T fragments (shared across the 2 s-chunks)
    bf16x8 af[2][4], bv[2][4];
#pragma unroll
    for (int ks = 0; ks < 2; ++ks)
#pragma unroll
      for (int jc = 0; jc < 4; ++jc) {
        int row = jc * 16 + a_, q = ks * 4 + q4;
        af[ks][jc] = *(const bf16x8*)&Ks[(row * 8 + (q ^ (row & 7))) * 8];
        bv[ks][jc] = *(const bf16x8*)&Vt[(row * 8 + (q ^ (row & 7))) * 8];
      }
#pragma unroll
    for (int cc = 0; cc < 2; ++cc) {
      int sbase = (cc * 4 + w) * 16;
      // S^T = K Q^T : rows t = jc*16+q4*4+r, col s = sbase + a_ (log2 domain)
      floatx4 sc[4];
#pragma unroll
      for (int jc = 0; jc < 4; ++jc) sc[jc] = (floatx4)(0.0f);
#pragma unroll
      for (int ks = 0; ks < 2; ++ks) {
        int row = sbase + a_, q = ks * 4 + q4;
        bf16x8 bq = *(const bf16x8*)&Qs[(row * 8 + (q ^ (row & 7))) * 8];
#pragma unroll
        for (int jc = 0; jc < 4; ++jc)
          sc[jc] = __builtin_amdgcn_mfma_f32_16x16x32_bf16(af[ks][jc], bq,
                                                           sc[jc], 0, 0, 0);
      }
      // online softmax (exp2 domain): lane's 16 values share column s
      float mx = sc[0][0];
#pragma unroll
      for (int jc = 0; jc < 4; ++jc)
#pragma unroll
        for (int r = 0; r < 4; ++r) mx = fmaxf(mx, sc[jc][r]);
      mx = fmaxf(mx, __shfl_xor(mx, 16));
      mx = fmaxf(mx, __shfl_xor(mx, 32));
      float mnew = fmaxf(mrow[cc], mx);
      float alpha = __builtin_amdgcn_exp2f(mrow[cc] - mnew);
      mrow[cc] = mnew;
      float ps = 0.f;
      int prow = w * 16 + a_;
#pragma unroll
      for (int jc = 0; jc < 4; ++jc) {
        bf16x4 pb;
#pragma unroll
        for (int r = 0; r < 4; ++r) {
          float p = __builtin_amdgcn_exp2f(sc[jc][r] - mnew);
          ps += p;
          pb[r] = (__bf16)p;
        }
        int pc = jc * 2 + (q4 >> 1);
        *(bf16x4*)&Ps[(prow * 8 + (pc ^ (prow & 7))) * 8 + (q4 & 1) * 4] = pb;
      }
      ps += __shfl_xor(ps, 16);
      ps += __shfl_xor(ps, 32);
      lrow[cc] = lrow[cc] * alpha + ps;
      float aal[4];
#pragma unroll
      for (int r = 0; r < 4; ++r) aal[r] = __shfl(alpha, q4 * 4 + r);
#pragma unroll
      for (int jc = 0; jc < 4; ++jc) {
        floatx4 t = accO[cc][jc];
#pragma unroll
        for (int r = 0; r < 4; ++r) t[r] *= aal[r];
        accO[cc][jc] = t;
      }
      // O += P V  (Ps rows wave-private; same-wave LDS RAW ordered via lgkmcnt)
#pragma unroll
      for (int ks = 0; ks < 2; ++ks) {
        int q = ks * 4 + q4;
        bf16x8 ap = *(const bf16x8*)&Ps[(prow * 8 + (q ^ (prow & 7))) * 8];
#pragma unroll
        for (int jc = 0; jc < 4; ++jc)
          accO[cc][jc] = __builtin_amdgcn_mfma_f32_16x16x32_bf16(
              ap, bv[ks][jc], accO[cc][jc], 0, 0, 0);
      }
    }
    __syncthreads();
  }
  // epilogue: row = s0+(cc*4+w)*16+q4*4+r, col = jc*16+a_  (into Q slice)
#pragma unroll
  for (int cc = 0; cc < 2; ++cc) {
    float inv = 1.f / lrow[cc];
    float linv[4];
#pragma unroll
    for (int r = 0; r < 4; ++r) linv[r] = __shfl(inv, q4 * 4 + r);
    int srow = s0 + (cc * 4 + w) * 16 + q4 * 4;
#pragma unroll
    for (int r = 0; r < 4; ++r)
#pragma unroll
      for (int jc = 0; jc < 4; ++jc)
        Qg[(size_t)(srow + r) * QS_ + jc * 16 + a_] =
            (__bf16)(accO[cc][jc][r] * linv[r]);
  }
}

// ---------------- add + l2norm: X = l2norm(X + MH), Ab = bf16(X) ----------
__global__ __launch_bounds__(256) void addnorm_kernel(
    float* __restrict__ X, const __bf16* __restrict__ MH, __bf16* __restrict__ Ab) {
  int row = blockIdx.x * 4 + (threadIdx.x >> 6);
  int ln = threadIdx.x & 63;
  size_t off = (size_t)row * E_ + ln * 8;
  float xv[8];
  *(float4*)&xv[0] = *(const float4*)(X + off);
  *(float4*)&xv[4] = *(const float4*)(X + off + 4);
  bf16x8 mh = *(const bf16x8*)(MH + off);
  float ss = 0.f;
#pragma unroll
  for (int j = 0; j < 8; ++j) {
    xv[j] += (float)mh[j];
    ss += xv[j] * xv[j];
  }
#pragma unroll
  for (int o = 1; o < 64; o <<= 1) ss += __shfl_xor(ss, o);
  float inv = rsqrtf(fmaxf(ss, 1e-12f));
  bf16x8 ob;
#pragma unroll
  for (int j = 0; j < 8; ++j) {
    xv[j] *= inv;
    ob[j] = (__bf16)xv[j];
  }
  *(float4*)(X + off) = *(float4*)&xv[0];
  *(float4*)(X + off + 4) = *(float4*)&xv[4];
  *(bf16x8*)(Ab + off) = ob;
}

// ---------------- conv-pool: pooled[b][l] = dot(X[b, 5l:5l+5, :], Wc)+bc ---
__global__ __launch_bounds__(256) void conv_pool_kernel(
    const float* __restrict__ X, const float* __restrict__ Wc,
    const float* __restrict__ bc, float* __restrict__ pooled) {
  int wid = blockIdx.x * 4 + (threadIdx.x >> 6);
  int ln = threadIdx.x & 63;
  int b = wid / LOUT_, l = wid % LOUT_;
  const float* xr = X + (size_t)b * S_ * E_ + (size_t)l * 5 * E_;
  float v = 0.f;
#pragma unroll
  for (int j = 0; j < 10; ++j) {
    int i = (j * 64 + ln) * 4;
    float4 x4 = *(const float4*)(xr + i);
    float4 w4 = *(const float4*)(Wc + i);
    v += x4.x * w4.x + x4.y * w4.y + x4.z * w4.z + x4.w * w4.w;
  }
#pragma unroll
  for (int o = 32; o >= 1; o >>= 1) v += __shfl_down(v, o);
  if (ln == 0) pooled[b * LOUT_ + l] = v + bc[0];
}

// ---------------- dense + softmax: out[b] = softmax(pooled[b] @ Wd + bd) ---
__global__ __launch_bounds__(256) void dense_softmax_kernel(
    const float* __restrict__ pooled, const float* __restrict__ Wd,
    const float* __restrict__ bd, float* __restrict__ out) {
  __shared__ float pl[LOUT_];
  __shared__ float red[256];
  __shared__ float lg[O_];
  int b = blockIdx.x, tid = threadIdx.x;
  if (tid < LOUT_) pl[tid] = pooled[b * LOUT_ + tid];
  __syncthreads();
  for (int o = tid; o < O_; o += 256) {
    float acc = bd[o];
#pragma unroll 6
    for (int l = 0; l < LOUT_; ++l) acc += pl[l] * Wd[l * O_ + o];
    lg[o] = acc;
  }
  __syncthreads();
  float mx = -3.0e38f;
  for (int o = tid; o < O_; o += 256) mx = fmaxf(mx, lg[o]);
  red[tid] = mx;
  __syncthreads();
  for (int s2 = 128; s2 > 0; s2 >>= 1) {
    if (tid < s2) red[tid] = fmaxf(red[tid], red[tid + s2]);
    __syncthreads();
  }
  mx = red[0];
  __syncthreads();
  float se = 0.f;
  for (int o = tid; o < O_; o += 256) {
    float e = __expf(lg[o] - mx);
    lg[o] = e;
    se += e;
  }
  red[tid] = se;
  __syncthreads();
  for (int s2 = 128; s2 > 0; s2 >>= 1) {
    if (tid < s2) red[tid] += red[tid + s2];
    __syncthreads();
  }
  float inv = 1.f / red[0];
  for (int o = tid; o < O_; o += 256) out[(size_t)b * O_ + o] = lg[o] * inv;
}

extern "C" void kernel_launch(void* const* d_in, const int* in_sizes, int n_in,
                              void* d_out, int out_size, void* d_ws, size_t ws_size,
                              hipStream_t stream) {
  const int* tokens = (const int*)d_in[0];
  const float* emb = (const float*)d_in[1];
  const float* Wq = (const float*)d_in[2];
  const float* bq = (const float*)d_in[3];
  const float* Wk = (const float*)d_in[4];
  const float* bk = (const float*)d_in[5];
  const float* Wv = (const float*)d_in[6];
  const float* bv = (const float*)d_in[7];
  const float* Wo = (const float*)d_in[8];
  const float* bo = (const float*)d_in[9];
  const float* W1 = (const float*)d_in[10];
  const float* b1 = (const float*)d_in[11];
  const float* W2 = (const float*)d_in[12];
  const float* b2 = (const float*)d_in[13];
  const float* Wc = (const float*)d_in[14];
  const float* bc = (const float*)d_in[15];
  const float* Wd = (const float*)d_in[16];
  const float* bd = (const float*)d_in[17];
  float* out = (float*)d_out;

  // ws layout (bytes):
  //  X f32        [0,   64M)
  //  Ab bf16      [64M, 96M)
  //  QKVb bf16    [96M, 192M)   [32768][1536]; FF1 out reuses [96M,160M)
  //  MH bf16      [192M,224M)   [32768][512]
  //  Wt bf16      [224M,240M)   qkv 6M | Wo 2M | W1 4M | W2 4M
  //  qkvbias f32  [240M, +24K)
  //  pooled f32   [..., +26.2K)
  char* ws = (char*)d_ws;
  float* X = (float*)ws;
  __bf16* Ab = (__bf16*)(ws + 67108864);
  __bf16* QKVb = (__bf16*)(ws + 100663296);
  __bf16* FF1b = QKVb;  // reuse (QKV dead after Wo gemm)
  __bf16* MHb = (__bf16*)(ws + 201326592);
  __bf16* Wt = (__bf16*)(ws + 234881024);
  __bf16* Wt_qkv = Wt;                 // [L][1536][512]
  __bf16* Wt_o = Wt + 3145728;         // [L][512][512]
  __bf16* Wt_1 = Wt + 4194304;         // [L][1024][512]
  __bf16* Wt_2 = Wt + 6291456;         // [L][512][1024]
  float* qkvbias = (float*)(ws + 251658240);
  float* pooled = qkvbias + 6144;

  dim3 tb(32, 8);
  transpose_bf16<<<dim3(2, 16, 32), tb, 0, stream>>>(Wq, Wt_qkv + 0,      512, 64, 32768, 786432, 32768);
  transpose_bf16<<<dim3(2, 16, 32), tb, 0, stream>>>(Wk, Wt_qkv + 262144, 512, 64, 32768, 786432, 32768);
  transpose_bf16<<<dim3(2, 16, 32), tb, 0, stream>>>(Wv, Wt_qkv + 524288, 512, 64, 32768, 786432, 32768);
  transpose_bf16<<<dim3(16, 16, 4), tb, 0, stream>>>(Wo, Wt_o, 512, 512, 262144, 0, 262144);
  transpose_bf16<<<dim3(32, 16, 4), tb, 0, stream>>>(W1, Wt_1, 512, 1024, 524288, 0, 524288);
  transpose_bf16<<<dim3(16, 32, 4), tb, 0, stream>>>(W2, Wt_2, 1024, 512, 524288, 0, 524288);
  bias_concat<<<dim3(24), dim3(256), 0, stream>>>(bq, bk, bv, qkvbias);

  embed_kernel<<<dim3(BS_ * E_ / 4 / 256), dim3(256), 0, stream>>>(tokens, emb, X, Ab);

  dim3 blk(256);
  for (int i = 0; i < L_; ++i) {
    gemm_bf16<0, 0, 0, 1, 1, 8><<<dim3(256 * 12), blk, 0, stream>>>(
        Ab, Wt_qkv + (size_t)i * 786432, qkvbias + i * QS_, nullptr, nullptr,
        QKVb, QS_, 512, 12);
    attn_bf16<<<dim3(4, 8, 64), blk, 0, stream>>>(QKVb);
    gemm_bf16<0, 0, 0, 1, 0, 8><<<dim3(256 * 4), blk, 0, stream>>>(
        QKVb, Wt_o + (size_t)i * 262144, bo + i * E_, nullptr, nullptr, MHb,
        512, QS_, 4);
    addnorm_kernel<<<dim3(BS_ / 4), blk, 0, stream>>>(X, MHb, Ab);
    gemm_bf16<1, 0, 0, 1, 0, 8><<<dim3(256 * 8), blk, 0, stream>>>(
        Ab, Wt_1 + (size_t)i * 524288, b1 + (size_t)i * 2 * E_, nullptr, nullptr,
        FF1b, 1024, 512, 8);
    gemm_bf16<0, 1, 1, 1, 0, 16><<<dim3(256 * 4), blk, 0, stream>>>(
        FF1b, Wt_2 + (size_t)i * 524288, b2 + (size_t)i * E_, X, X, Ab,
        512, 1024, 4);
  }
  conv_pool_kernel<<<dim3(BS_ * LOUT_ / S_ / 4), blk, 0, stream>>>(X, Wc, bc, pooled);
  dense_softmax_kernel<<<dim3(B_), blk, 0, stream>>>(pooled, Wd, bd, out);
}